// Round 7
// baseline (541.113 us; speedup 1.0000x reference)
//
#include <hip/hip_runtime.h>
#include <stdint.h>

#define Bb 8
#define Cc 2048
#define Ee 1024

typedef unsigned short u16;
typedef __attribute__((ext_vector_type(8))) short short8;
typedef __attribute__((ext_vector_type(4))) float f32x4;

__device__ __forceinline__ u16 f2bf(float f){
    unsigned u = __builtin_bit_cast(unsigned, f);
    return (u16)((u + 0x7fffu + ((u >> 16) & 1u)) >> 16);   // RNE, finite inputs
}
__device__ __forceinline__ float bf2f(u16 h){
    return __builtin_bit_cast(float, ((unsigned)h) << 16);
}
__device__ __forceinline__ void gld16(const void* g, void* l){
    __builtin_amdgcn_global_load_lds(
        (const __attribute__((address_space(1))) unsigned int*)g,
        (__attribute__((address_space(3))) unsigned int*)l,
        16, 0, 0);
}
#define MFMA(a,b,c) __builtin_amdgcn_mfma_f32_16x16x32_bf16((a),(b),(c),0,0,0)
#define SBAR()  __builtin_amdgcn_s_barrier()
#define SCHED0() __builtin_amdgcn_sched_barrier(0)
#define LGKM8() asm volatile("s_waitcnt lgkmcnt(8)" ::: "memory")
#define LGKM4() asm volatile("s_waitcnt lgkmcnt(4)" ::: "memory")
#define LGKM0() asm volatile("s_waitcnt lgkmcnt(0)" ::: "memory")
#define VMCNT8() asm volatile("s_waitcnt vmcnt(8)" ::: "memory")
#define VMCNT6() asm volatile("s_waitcnt vmcnt(6)" ::: "memory")
#define VMCNT0() asm volatile("s_waitcnt vmcnt(0)" ::: "memory")

// ---------------- cast fp32 -> bf16 (vectorized) ----------------
__global__ __launch_bounds__(256) void k_cast(const float* __restrict__ s,
                                              u16* __restrict__ d, long n4){
    long i = (long)blockIdx.x * 256 + threadIdx.x;
    const long stride = (long)gridDim.x * 256;
    for (; i < n4; i += stride){
        float4 f = ((const float4*)s)[i];
        ushort4 o = make_ushort4(f2bf(f.x), f2bf(f.y), f2bf(f.z), f2bf(f.w));
        ((ushort4*)d)[i] = o;
    }
}

// ------ fused: x fp32 -> xb bf16 (straight) + xbT bf16 (transposed) ------
__global__ __launch_bounds__(256) void k_cast_xt(const float* __restrict__ src,
                                                 u16* __restrict__ xb,
                                                 u16* __restrict__ xbT){
    __shared__ float tile[32][33];
    const int b = blockIdx.z;
    src += (long)b * Cc * Ee;
    xb  += (long)b * Cc * Ee;
    xbT += (long)b * Cc * Ee;
    const int c0 = blockIdx.x * 32;   // E-dim block
    const int r0 = blockIdx.y * 32;   // C-dim block
    const int tx = threadIdx.x & 31;
    const int ty = threadIdx.x >> 5;  // 0..7
    #pragma unroll
    for (int p = 0; p < 4; ++p){
        float v = src[(long)(r0 + ty + p*8) * Ee + c0 + tx];
        tile[ty + p*8][tx] = v;
        xb[(long)(r0 + ty + p*8) * Ee + c0 + tx] = f2bf(v);
    }
    __syncthreads();
    #pragma unroll
    for (int p = 0; p < 4; ++p)
        xbT[(long)(c0 + ty + p*8) * Cc + r0 + tx] = f2bf(tile[tx][ty + p*8]);
}

// ======== 256x256 NT GEMM — cross-phase pipelined reads, kh-half slot ring ========
// C[m,n] = scale*sum_k A[m,k]B[n,k] (+bias). 8 waves (2M x 4N), BK=64.
// LDS: A ring 4 slots x 16KiB (slot g=(2t+j)&3 holds kh-half j of tile t:
//      [256 rows][32 cols] bf16, chunk-swizzled c' = c ^ (row&3)); B same at +64KiB.
// Phase p's MFMA consumes frags read in phase p-1 (counted lgkm: wait = just-issued).
// Phase reads: p0->R(p1)=A(qm1,kh0):4 | p1->R(p2)=A(qm0,kh1)+B(kh1):8
//              p2->R(p3)=A(qm1,kh1):4 | p3->R(p0')=A(qm0,kh0,t+1)+B(kh0,t+1):8
// Stages (2 gld16 = 1 half/phase): p0:A-kh1(t+1) p1:B-kh1(t+1) p2:A-kh0(t+2) p3:B-kh0(t+2)
// Waits: vmcnt(6) at p0-end (forces kh1(t), needed by p1's reads) and p2-end
// (forces kh0(t+1), needed by p3's reads). Slot overwrites are barrier-separated
// from last reads (ring depth 2 tiles). Last 2 tiles drain (vmcnt 0).
template<int BIAS_MODE, int OUT_F32>
__global__ __launch_bounds__(512, 2)
void k_gemm256(const u16* __restrict__ A, const u16* __restrict__ Bm,
               void* __restrict__ Cout, const float* __restrict__ bias,
               int N, int K, long sA, long sB, long sC, float scale)
{
    __shared__ __attribute__((aligned(16))) char smem[131072];

    // ---- bijective XCD swizzle (nwg % 8 == 0 for all launches here)
    const int gx = gridDim.x, gy = gridDim.y;
    const int nwg = gx * gy * gridDim.z;
    const int lin = blockIdx.x + gx * (blockIdx.y + gy * blockIdx.z);
    const int swz = (lin & 7) * (nwg >> 3) + (lin >> 3);
    const int bx = swz % gx;
    const int tmp = swz / gx;
    const int by = tmp % gy;
    const int bz = tmp / gy;

    A  += (long)bz * sA;
    Bm += (long)bz * sB;
    u16*   Cm = (u16*)Cout + (OUT_F32 ? 0 : (long)bz * sC);
    float* Cf = (float*)Cout + (OUT_F32 ? (long)bz * sC : 0);

    const int tid  = threadIdx.x;
    const int lane = tid & 63;
    const int wave = tid >> 6;
    const int wr = wave >> 2;          // 0..1  (M half)
    const int wc = wave & 3;           // 0..3  (N quarter)
    const int tileM = bx * 256;
    const int tileN = by * 256;

    // ---- staging: per half-slot (256r x 32c = 16KiB) = 2 gld16/thread.
    // thread -> (row = tid>>2 (+128 for 2nd load), chunk = tid&3), src pre-swizzled.
    const int srow = tid >> 2;                   // 0..127
    const int schk = (tid & 3) ^ (srow & 3);     // inverse of read swizzle
    const u16* Ag = A  + (long)(tileM + srow) * K + schk * 8;
    const u16* Bg = Bm + (long)(tileN + srow) * K + schk * 8;
    const long rk128 = (long)128 * K;
    const int  ldst = tid * 16;                  // linear dest within 8KiB piece

    #define STGA(tt,j) { gld16(Ag + (long)(tt)*64 + (j)*32,         smem + ((tt)&1)*32768 + (j)*16384 + ldst); \
                         gld16(Ag + (long)(tt)*64 + (j)*32 + rk128, smem + ((tt)&1)*32768 + (j)*16384 + 8192 + ldst); }
    #define STGB(tt,j) { gld16(Bg + (long)(tt)*64 + (j)*32,         smem + 65536 + ((tt)&1)*32768 + (j)*16384 + ldst); \
                         gld16(Bg + (long)(tt)*64 + (j)*32 + rk128, smem + 65536 + ((tt)&1)*32768 + (j)*16384 + 8192 + ldst); }

    // ---- ds_read constants: addr = base(ab) + j*16384 + arow/brow + frag*1024 + cs
    const int lrow = lane & 15;
    const int lk   = lane >> 4;
    const int cs   = (lk ^ (lrow & 3)) << 4;             // swizzled 16B chunk
    const int arow = (wr*128 + lrow) * 64;
    const int brow = 65536 + (wc*64 + lrow) * 64;

    f32x4 acc[8][4];
    #pragma unroll
    for (int m = 0; m < 8; ++m)
        #pragma unroll
        for (int n = 0; n < 4; ++n)
            acc[m][n] = (f32x4){0.f,0.f,0.f,0.f};

    const int NT = K >> 6;
    short8 aE[4], aO[4], bE[4], bO[4];

    // ---- prologue: 6 halves; vmcnt(8) -> kh0(0) ready; pre-read R(p0 of t0)
    STGA(0,0); STGB(0,0); STGA(0,1); STGB(0,1); STGA(1,0); STGB(1,0);
    VMCNT8(); SBAR(); SCHED0();
    #pragma unroll
    for (int m = 0; m < 4; ++m) aE[m] = *(const short8*)(smem + arow + m*1024 + cs);
    #pragma unroll
    for (int n = 0; n < 4; ++n) bE[n] = *(const short8*)(smem + brow + n*1024 + cs);

    auto tile_body = [&](int t, int ab, int nb) __attribute__((always_inline)) {
        const bool g1 = (t + 1) < NT;
        const bool g2 = (t + 2) < NT;
        const bool dr = t >= NT - 2;

        // ===== p0: MFMA(qm0,kh0) [aE,bE]; read R(p1)=A(qm1,kh0); stage A-kh1(t+1)
        #pragma unroll
        for (int m = 0; m < 4; ++m) aO[m] = *(const short8*)(smem + ab + arow + (m+4)*1024 + cs);
        if (g1) STGA(t+1, 1);
        LGKM4(); SCHED0();
        __builtin_amdgcn_s_setprio(1);
        #pragma unroll
        for (int m = 0; m < 4; ++m)
            #pragma unroll
            for (int n = 0; n < 4; ++n)
                acc[m][n] = MFMA(aE[m], bE[n], acc[m][n]);
        __builtin_amdgcn_s_setprio(0);
        if (dr) { VMCNT0(); } else { VMCNT6(); }
        SBAR(); SCHED0();

        // ===== p1: MFMA(qm1,kh0) [aO,bE]; read R(p2)=A(qm0,kh1)+B(kh1); stage B-kh1(t+1)
        #pragma unroll
        for (int m = 0; m < 4; ++m) aE[m] = *(const short8*)(smem + ab + 16384 + arow + m*1024 + cs);
        #pragma unroll
        for (int n = 0; n < 4; ++n) bO[n] = *(const short8*)(smem + ab + 16384 + brow + n*1024 + cs);
        if (g1) STGB(t+1, 1);
        LGKM8(); SCHED0();
        __builtin_amdgcn_s_setprio(1);
        #pragma unroll
        for (int m = 0; m < 4; ++m)
            #pragma unroll
            for (int n = 0; n < 4; ++n)
                acc[m+4][n] = MFMA(aO[m], bE[n], acc[m+4][n]);
        __builtin_amdgcn_s_setprio(0);
        SBAR(); SCHED0();

        // ===== p2: MFMA(qm0,kh1) [aE,bO]; read R(p3)=A(qm1,kh1); stage A-kh0(t+2)
        #pragma unroll
        for (int m = 0; m < 4; ++m) aO[m] = *(const short8*)(smem + ab + 16384 + arow + (m+4)*1024 + cs);
        if (g2) STGA(t+2, 0);
        LGKM4(); SCHED0();
        __builtin_amdgcn_s_setprio(1);
        #pragma unroll
        for (int m = 0; m < 4; ++m)
            #pragma unroll
            for (int n = 0; n < 4; ++n)
                acc[m][n] = MFMA(aE[m], bO[n], acc[m][n]);
        __builtin_amdgcn_s_setprio(0);
        if (dr) { VMCNT0(); } else { VMCNT6(); }
        SBAR(); SCHED0();

        // ===== p3: MFMA(qm1,kh1) [aO,bO]; read R(p0')=A(qm0,kh0,t+1)+B(kh0,t+1); stage B-kh0(t+2)
        if (g1){
            #pragma unroll
            for (int m = 0; m < 4; ++m) aE[m] = *(const short8*)(smem + nb + arow + m*1024 + cs);
            #pragma unroll
            for (int n = 0; n < 4; ++n) bE[n] = *(const short8*)(smem + nb + brow + n*1024 + cs);
        }
        if (g2) STGB(t+2, 0);
        if (g1) { LGKM8(); } else { LGKM0(); }
        SCHED0();
        __builtin_amdgcn_s_setprio(1);
        #pragma unroll
        for (int m = 0; m < 4; ++m)
            #pragma unroll
            for (int n = 0; n < 4; ++n)
                acc[m+4][n] = MFMA(aO[m], bO[n], acc[m+4][n]);
        __builtin_amdgcn_s_setprio(0);
        SBAR(); SCHED0();
    };

    for (int t = 0; t < NT; t += 2){
        tile_body(t,     0,     32768);
        tile_body(t + 1, 32768, 0);
    }

    // ---- epilogue: C/D layout col=lane&15, row=(lane>>4)*4+j
    const int r0base = tileM + wr*128 + lk*4;
    const int cbase  = tileN + wc*64 + lrow;
    #pragma unroll
    for (int m = 0; m < 8; ++m){
        const int r0 = r0base + m*16;
        #pragma unroll
        for (int n = 0; n < 4; ++n){
            const int c = cbase + n*16;
            f32x4 v = acc[m][n];
            #pragma unroll
            for (int j = 0; j < 4; ++j){
                float val = v[j] * scale;
                if (BIAS_MODE == 1) val += bias[c];
                if (BIAS_MODE == 2) val += bias[r0 + j];
                if (OUT_F32) Cf[(long)(r0 + j) * N + c] = val;
                else         Cm[(long)(r0 + j) * N + c] = f2bf(val);
            }
        }
    }
    #undef STGA
    #undef STGB
}

// ---------------- row softmax, in-place on bf16 [rows x 2048] ----------------
__global__ __launch_bounds__(256) void k_softmax(u16* __restrict__ P){
    u16* p = P + (long)blockIdx.x * Cc;
    const int tid = threadIdx.x;
    short8 raw = *(const short8*)(p + tid * 8);
    float v[8];
    float mx = -3.0e38f;
    #pragma unroll
    for (int i = 0; i < 8; ++i){ v[i] = bf2f((u16)raw[i]); mx = fmaxf(mx, v[i]); }
    #pragma unroll
    for (int o = 32; o > 0; o >>= 1) mx = fmaxf(mx, __shfl_xor(mx, o));
    __shared__ float redm[4];
    if ((tid & 63) == 0) redm[tid >> 6] = mx;
    __syncthreads();
    mx = fmaxf(fmaxf(redm[0], redm[1]), fmaxf(redm[2], redm[3]));
    float s = 0.f;
    #pragma unroll
    for (int i = 0; i < 8; ++i){ v[i] = __expf(v[i] - mx); s += v[i]; }
    #pragma unroll
    for (int o = 32; o > 0; o >>= 1) s += __shfl_xor(s, o);
    __shared__ float reds[4];
    if ((tid & 63) == 0) reds[tid >> 6] = s;
    __syncthreads();
    s = reds[0] + reds[1] + reds[2] + reds[3];
    const float inv = 1.f / s;
    short8 o8;
    #pragma unroll
    for (int i = 0; i < 8; ++i) o8[i] = (short)f2bf(v[i] * inv);
    *(short8*)(p + tid * 8) = o8;
}

static inline int cast_grid(long n4){
    long g = (n4 + 255) / 256;
    return (int)(g > 2048 ? 2048 : g);
}

extern "C" void kernel_launch(void* const* d_in, const int* in_sizes, int n_in,
                              void* d_out, int out_size, void* d_ws, size_t ws_size,
                              hipStream_t stream)
{
    const float* x     = (const float*)d_in[0];
    const float* fc_w  = (const float*)d_in[1];
    const float* fc_b  = (const float*)d_in[2];
    const float* altw  = (const float*)d_in[3];
    const float* altb  = (const float*)d_in[4];
    const float* vfc_w = (const float*)d_in[5];
    const float* vfc_b = (const float*)d_in[6];
    float* out = (float*)d_out;   // reference output is fp32

    char* ws = (char*)d_ws;
    const size_t nBCE = (size_t)Bb * Cc * Ee;            // 16,777,216 elements
    u16* xb   = (u16*)(ws);                              // [B][C][E]
    u16* xbT  = (u16*)(ws + 2 * nBCE);                   // [B][E][C]
    u16* P    = (u16*)(ws);                              // [B][C][C] (aliases xb+xbT, dead by then)
    u16* y    = (u16*)(ws + 4 * nBCE);                   // [B][C][E]
    u16* z    = (u16*)(ws + 6 * nBCE);                   // [B][C][E]   z[b][k][e] = yx[b,e,k]
    u16* vxT  = (u16*)(ws + 8 * nBCE);                   // [B][E][C]   vxT[b][f][k] = vx[b,k,f]
    u16* fcwb = (u16*)(ws + 10 * nBCE);                  // [E][E]
    u16* vfwb = fcwb + (size_t)Ee * Ee;
    u16* awb  = vfwb + (size_t)Ee * Ee;                  // [C][C]

    // 1) casts (x: fused straight+transpose, single fp32 read)
    k_cast_xt<<<dim3(Ee / 32, Cc / 32, Bb), 256, 0, stream>>>(x, xb, xbT);
    k_cast<<<cast_grid((long)Ee * Ee / 4), 256, 0, stream>>>(fc_w, fcwb, (long)Ee * Ee / 4);
    k_cast<<<cast_grid((long)Ee * Ee / 4), 256, 0, stream>>>(vfc_w, vfwb, (long)Ee * Ee / 4);
    k_cast<<<cast_grid((long)Cc * Cc / 4), 256, 0, stream>>>(altw, awb, (long)Cc * Cc / 4);

    const long sBCE = (long)Cc * Ee;
    const long sBCC = (long)Cc * Cc;
    dim3 blk(512);

    // 2) y[b][c][f] = sum_e xb[c,e] fcw[f,e] + fc_b[f]        M=C,N=E,K=E
    k_gemm256<1, 0><<<dim3(Cc/256, Ee/256, Bb), blk, 0, stream>>>(
        xb, fcwb, y, fc_b, Ee, Ee, sBCE, 0, sBCE, 1.f);

    // 3) vxT[b][f][k] = sum_e vfcw[f,e] xb[k,e] + vfc_b[f]    M=E,N=C,K=E (bias per row)
    k_gemm256<2, 0><<<dim3(Ee/256, Cc/256, Bb), blk, 0, stream>>>(
        vfwb, xb, vxT, vfc_b, Cc, Ee, 0, sBCE, sBCE, 1.f);

    // 4) z[b][k][e] = sum_c altw[k,c] xT[e,c] + alt_b[k]      M=C,N=E,K=C (bias per row)
    k_gemm256<2, 0><<<dim3(Cc/256, Ee/256, Bb), blk, 0, stream>>>(
        awb, xbT, z, altb, Ee, Cc, 0, sBCE, sBCE, 1.f);

    // 5) P[b][c][k] = (1/sqrt(C)) * sum_e y[c,e] z[k,e]       M=C,N=C,K=E
    k_gemm256<0, 0><<<dim3(Cc/256, Cc/256, Bb), blk, 0, stream>>>(
        y, z, P, nullptr, Cc, Ee, sBCE, sBCE, sBCC, 0.022097086912079608f);

    // 6) softmax rows of P (in place)
    k_softmax<<<Bb * Cc, 256, 0, stream>>>(P);

    // 7) out[b][c][e] = sum_k P[c,k] vxT[e,k] -> fp32         M=C,N=E,K=C
    k_gemm256<0, 1><<<dim3(Cc/256, Ee/256, Bb), blk, 0, stream>>>(
        P, vxT, out, nullptr, Ee, Cc, sBCC, sBCE, sBCE, 1.f);
}

// Round 8
// 339.269 us; speedup vs baseline: 1.5949x; 1.5949x over previous
//
#include <hip/hip_runtime.h>
#include <stdint.h>

#define Bb 8
#define Cc 2048
#define Ee 1024

typedef unsigned short u16;
typedef __attribute__((ext_vector_type(8))) short short8;
typedef __attribute__((ext_vector_type(4))) float f32x4;

__device__ __forceinline__ u16 f2bf(float f){
    unsigned u = __builtin_bit_cast(unsigned, f);
    return (u16)((u + 0x7fffu + ((u >> 16) & 1u)) >> 16);   // RNE, finite inputs
}
__device__ __forceinline__ float bf2f(u16 h){
    return __builtin_bit_cast(float, ((unsigned)h) << 16);
}
__device__ __forceinline__ void gld16(const void* g, void* l){
    __builtin_amdgcn_global_load_lds(
        (const __attribute__((address_space(1))) unsigned int*)g,
        (__attribute__((address_space(3))) unsigned int*)l,
        16, 0, 0);
}
#define MFMA(a,b,c) __builtin_amdgcn_mfma_f32_16x16x32_bf16((a),(b),(c),0,0,0)
#define SBAR()  __builtin_amdgcn_s_barrier()
#define SCHED0() __builtin_amdgcn_sched_barrier(0)
#define LGKM8() asm volatile("s_waitcnt lgkmcnt(8)" ::: "memory")
#define LGKM4() asm volatile("s_waitcnt lgkmcnt(4)" ::: "memory")
#define LGKM0() asm volatile("s_waitcnt lgkmcnt(0)" ::: "memory")
#define VMCNT0() asm volatile("s_waitcnt vmcnt(0)" ::: "memory")

// ---------------- cast fp32 -> bf16 (vectorized) ----------------
__global__ __launch_bounds__(256) void k_cast(const float* __restrict__ s,
                                              u16* __restrict__ d, long n4){
    long i = (long)blockIdx.x * 256 + threadIdx.x;
    const long stride = (long)gridDim.x * 256;
    for (; i < n4; i += stride){
        float4 f = ((const float4*)s)[i];
        ushort4 o = make_ushort4(f2bf(f.x), f2bf(f.y), f2bf(f.z), f2bf(f.w));
        ((ushort4*)d)[i] = o;
    }
}

// ------ fused: x fp32 -> xb bf16 (straight) + xbT bf16 (transposed) ------
__global__ __launch_bounds__(256) void k_cast_xt(const float* __restrict__ src,
                                                 u16* __restrict__ xb,
                                                 u16* __restrict__ xbT){
    __shared__ float tile[32][33];
    const int b = blockIdx.z;
    src += (long)b * Cc * Ee;
    xb  += (long)b * Cc * Ee;
    xbT += (long)b * Cc * Ee;
    const int c0 = blockIdx.x * 32;   // E-dim block
    const int r0 = blockIdx.y * 32;   // C-dim block
    const int tx = threadIdx.x & 31;
    const int ty = threadIdx.x >> 5;  // 0..7
    #pragma unroll
    for (int p = 0; p < 4; ++p){
        float v = src[(long)(r0 + ty + p*8) * Ee + c0 + tx];
        tile[ty + p*8][tx] = v;
        xb[(long)(r0 + ty + p*8) * Ee + c0 + tx] = f2bf(v);
    }
    __syncthreads();
    #pragma unroll
    for (int p = 0; p < 4; ++p)
        xbT[(long)(c0 + ty + p*8) * Cc + r0 + tx] = f2bf(tile[tx][ty + p*8]);
}

// ====== 256x256 NT GEMM — 1 barrier/K-tile, RAW-free cluster walk ======
// C[m,n] = scale*sum_k A[m,k]B[n,k] (+bias); A:[M,K], B:[N,K] bf16 row-major.
// 512 thr = 8 waves (2M x 4N); BK=64; LDS 128KiB double-buffered (R6 layout).
// Per K-tile: 8 gld16 for t+1 up-front; 4 MFMA clusters ordered so ADJACENT
// clusters accumulate into DIFFERENT acc quadrants (no C-in RAW -> MFMA pipe
// drains overlap the next cluster's reads/issue):
//   q0(m0-3,kk0) q1(m4-7,kk0) q2(m0-3,kk1) q3(m4-7,kk1); boundary q3->q0' also disjoint.
// Read batches (FIFO ds returns -> counted lgkm): [aE,bE,aO:12] LGKM4 q0
//   [aE<-kk1,bO:8] LGKM8 q1  [aO<-kk1:4] LGKM4 q2  LGKM0 q3 -> VMCNT0 SBAR.
// LDS swizzle: 16B-chunk c at c ^ (row&7); pre-swizzled global source (0 conflicts).
template<int BIAS_MODE, int OUT_F32>
__global__ __launch_bounds__(512, 2)
void k_gemm256(const u16* __restrict__ A, const u16* __restrict__ Bm,
               void* __restrict__ Cout, const float* __restrict__ bias,
               int N, int K, long sA, long sB, long sC, float scale)
{
    __shared__ __attribute__((aligned(16))) char smem[131072];

    // ---- bijective XCD swizzle (nwg % 8 == 0 for all launches here)
    const int gx = gridDim.x, gy = gridDim.y;
    const int nwg = gx * gy * gridDim.z;
    const int lin = blockIdx.x + gx * (blockIdx.y + gy * blockIdx.z);
    const int swz = (lin & 7) * (nwg >> 3) + (lin >> 3);
    const int bx = swz % gx;
    const int tmp = swz / gx;
    const int by = tmp % gy;
    const int bz = tmp / gy;

    A  += (long)bz * sA;
    Bm += (long)bz * sB;
    u16*   Cm = (u16*)Cout + (OUT_F32 ? 0 : (long)bz * sC);
    float* Cf = (float*)Cout + (OUT_F32 ? (long)bz * sC : 0);

    const int tid  = threadIdx.x;
    const int lane = tid & 63;
    const int wave = tid >> 6;
    const int wr = wave >> 2;          // 0..1  (M half)
    const int wc = wave & 3;           // 0..3  (N quarter)
    const int tileM = bx * 256;
    const int tileN = by * 256;

    // ---- staging constants: unit = 64 rows x 64 cols (8KiB) = 1 gld16/thread
    const int srow   = tid >> 3;                 // 0..63 (row within unit)
    const int schunk = (tid & 7) ^ (srow & 7);   // pre-swizzled 16B chunk
    const u16* Ag = A  + (long)(tileM + srow) * K + schunk * 8;
    const u16* Bg = Bm + (long)(tileN + srow) * K + schunk * 8;
    const long uK = (long)64 * K;                // global stride per unit
    const int  ldst = tid * 16;                  // linear LDS dest

    // ---- ds_read constants (swizzled chunk)
    const int lrow = lane & 15;
    const int lk   = lane >> 4;                  // 0..3
    const int sw   = lrow & 7;
    const int cs0  = ((0 + lk) ^ sw) * 16;       // kk=0 chunk byte
    const int cs1  = ((4 + lk) ^ sw) * 16;       // kk=1 chunk byte
    const int arow0 = (wr*128 + lrow) * 128;             // A row byte off in tile
    const int brow0 = 32768 + (wc*64 + lrow) * 128;      // B row byte off in tile

    f32x4 acc[8][4];
    #pragma unroll
    for (int m = 0; m < 8; ++m)
        #pragma unroll
        for (int n = 0; n < 4; ++n)
            acc[m][n] = (f32x4){0.f,0.f,0.f,0.f};

    char* sm = smem;
    // ---- prologue: stage tile 0 into buf0, full drain (one-time)
    #pragma unroll
    for (int u = 0; u < 4; ++u) gld16(Bg + u*uK, sm + 32768 + u*8192 + ldst);
    #pragma unroll
    for (int u = 0; u < 4; ++u) gld16(Ag + u*uK, sm + u*8192 + ldst);
    __syncthreads();

    const int NT = K >> 6;
    short8 aE[4], aO[4], bE[4], bO[4];

    for (int t = 0; t < NT; ++t){
        const bool pref = (t + 1) < NT;
        char* cbuf = sm + ((t & 1) << 16);
        char* nbuf = sm + (((t + 1) & 1) << 16);
        const u16* Agt = Ag + (long)(t + 1) * 64;
        const u16* Bgt = Bg + (long)(t + 1) * 64;

        // ---- issue next tile's staging up-front (8 loads; land during compute)
        if (pref){
            gld16(Agt + 0*uK, nbuf + 0*8192 + ldst);
            gld16(Agt + 1*uK, nbuf + 1*8192 + ldst);
            gld16(Agt + 2*uK, nbuf + 2*8192 + ldst);
            gld16(Agt + 3*uK, nbuf + 3*8192 + ldst);
            gld16(Bgt + 0*uK, nbuf + 32768 + 0*8192 + ldst);
            gld16(Bgt + 1*uK, nbuf + 32768 + 1*8192 + ldst);
            gld16(Bgt + 2*uK, nbuf + 32768 + 2*8192 + ldst);
            gld16(Bgt + 3*uK, nbuf + 32768 + 3*8192 + ldst);
        }

        // ---- batch1: aE(m0-3,kk0), bE(kk0), aO(m4-7,kk0)  [12 reads]
        #pragma unroll
        for (int m = 0; m < 4; ++m) aE[m] = *(const short8*)(cbuf + arow0 + m*2048 + cs0);
        #pragma unroll
        for (int n = 0; n < 4; ++n) bE[n] = *(const short8*)(cbuf + brow0 + n*2048 + cs0);
        #pragma unroll
        for (int m = 0; m < 4; ++m) aO[m] = *(const short8*)(cbuf + arow0 + (m+4)*2048 + cs0);

        LGKM4(); SCHED0();                       // aE,bE ready (aO may be in flight)
        __builtin_amdgcn_s_setprio(1);
        #pragma unroll
        for (int m = 0; m < 4; ++m)              // q0: acc[0-3]
            #pragma unroll
            for (int n = 0; n < 4; ++n)
                acc[m][n] = MFMA(aE[m], bE[n], acc[m][n]);
        __builtin_amdgcn_s_setprio(0);

        // ---- batch2: aE <- (m0-3,kk1), bO(kk1)  [8 reads]
        #pragma unroll
        for (int m = 0; m < 4; ++m) aE[m] = *(const short8*)(cbuf + arow0 + m*2048 + cs1);
        #pragma unroll
        for (int n = 0; n < 4; ++n) bO[n] = *(const short8*)(cbuf + brow0 + n*2048 + cs1);
        LGKM8(); SCHED0();                       // aO ready (batch2 in flight)
        __builtin_amdgcn_s_setprio(1);
        #pragma unroll
        for (int m = 0; m < 4; ++m)              // q1: acc[4-7] (disjoint from q0)
            #pragma unroll
            for (int n = 0; n < 4; ++n)
                acc[m+4][n] = MFMA(aO[m], bE[n], acc[m+4][n]);
        __builtin_amdgcn_s_setprio(0);

        // ---- batch3: aO <- (m4-7,kk1)  [4 reads]
        #pragma unroll
        for (int m = 0; m < 4; ++m) aO[m] = *(const short8*)(cbuf + arow0 + (m+4)*2048 + cs1);
        LGKM4(); SCHED0();                       // aE(kk1),bO ready (batch3 in flight)
        __builtin_amdgcn_s_setprio(1);
        #pragma unroll
        for (int m = 0; m < 4; ++m)              // q2: acc[0-3] (disjoint from q1)
            #pragma unroll
            for (int n = 0; n < 4; ++n)
                acc[m][n] = MFMA(aE[m], bO[n], acc[m][n]);
        __builtin_amdgcn_s_setprio(0);

        LGKM0(); SCHED0();                       // aO(kk1) ready
        __builtin_amdgcn_s_setprio(1);
        #pragma unroll
        for (int m = 0; m < 4; ++m)              // q3: acc[4-7] (disjoint from q2 and next q0)
            #pragma unroll
            for (int n = 0; n < 4; ++n)
                acc[m+4][n] = MFMA(aO[m], bO[n], acc[m+4][n]);
        __builtin_amdgcn_s_setprio(0);

        // ---- tile boundary: own staging landed + all waves done reading cbuf
        VMCNT0(); SBAR(); SCHED0();
    }

    // ---- epilogue: C/D layout col=lane&15, row=(lane>>4)*4+j
    const int r0base = tileM + wr*128 + lk*4;
    const int cbase  = tileN + wc*64 + lrow;
    #pragma unroll
    for (int m = 0; m < 8; ++m){
        const int r0 = r0base + m*16;
        #pragma unroll
        for (int n = 0; n < 4; ++n){
            const int c = cbase + n*16;
            f32x4 v = acc[m][n];
            #pragma unroll
            for (int j = 0; j < 4; ++j){
                float val = v[j] * scale;
                if (BIAS_MODE == 1) val += bias[c];
                if (BIAS_MODE == 2) val += bias[r0 + j];
                if (OUT_F32) Cf[(long)(r0 + j) * N + c] = val;
                else         Cm[(long)(r0 + j) * N + c] = f2bf(val);
            }
        }
    }
}

// ---------------- row softmax, in-place on bf16 [rows x 2048] ----------------
__global__ __launch_bounds__(256) void k_softmax(u16* __restrict__ P){
    u16* p = P + (long)blockIdx.x * Cc;
    const int tid = threadIdx.x;
    short8 raw = *(const short8*)(p + tid * 8);
    float v[8];
    float mx = -3.0e38f;
    #pragma unroll
    for (int i = 0; i < 8; ++i){ v[i] = bf2f((u16)raw[i]); mx = fmaxf(mx, v[i]); }
    #pragma unroll
    for (int o = 32; o > 0; o >>= 1) mx = fmaxf(mx, __shfl_xor(mx, o));
    __shared__ float redm[4];
    if ((tid & 63) == 0) redm[tid >> 6] = mx;
    __syncthreads();
    mx = fmaxf(fmaxf(redm[0], redm[1]), fmaxf(redm[2], redm[3]));
    float s = 0.f;
    #pragma unroll
    for (int i = 0; i < 8; ++i){ v[i] = __expf(v[i] - mx); s += v[i]; }
    #pragma unroll
    for (int o = 32; o > 0; o >>= 1) s += __shfl_xor(s, o);
    __shared__ float reds[4];
    if ((tid & 63) == 0) reds[tid >> 6] = s;
    __syncthreads();
    s = reds[0] + reds[1] + reds[2] + reds[3];
    const float inv = 1.f / s;
    short8 o8;
    #pragma unroll
    for (int i = 0; i < 8; ++i) o8[i] = (short)f2bf(v[i] * inv);
    *(short8*)(p + tid * 8) = o8;
}

static inline int cast_grid(long n4){
    long g = (n4 + 255) / 256;
    return (int)(g > 2048 ? 2048 : g);
}

extern "C" void kernel_launch(void* const* d_in, const int* in_sizes, int n_in,
                              void* d_out, int out_size, void* d_ws, size_t ws_size,
                              hipStream_t stream)
{
    const float* x     = (const float*)d_in[0];
    const float* fc_w  = (const float*)d_in[1];
    const float* fc_b  = (const float*)d_in[2];
    const float* altw  = (const float*)d_in[3];
    const float* altb  = (const float*)d_in[4];
    const float* vfc_w = (const float*)d_in[5];
    const float* vfc_b = (const float*)d_in[6];
    float* out = (float*)d_out;   // reference output is fp32

    char* ws = (char*)d_ws;
    const size_t nBCE = (size_t)Bb * Cc * Ee;            // 16,777,216 elements
    u16* xb   = (u16*)(ws);                              // [B][C][E]
    u16* xbT  = (u16*)(ws + 2 * nBCE);                   // [B][E][C]
    u16* P    = (u16*)(ws);                              // [B][C][C] (aliases xb+xbT, dead by then)
    u16* y    = (u16*)(ws + 4 * nBCE);                   // [B][C][E]
    u16* z    = (u16*)(ws + 6 * nBCE);                   // [B][C][E]   z[b][k][e] = yx[b,e,k]
    u16* vxT  = (u16*)(ws + 8 * nBCE);                   // [B][E][C]   vxT[b][f][k] = vx[b,k,f]
    u16* fcwb = (u16*)(ws + 10 * nBCE);                  // [E][E]
    u16* vfwb = fcwb + (size_t)Ee * Ee;
    u16* awb  = vfwb + (size_t)Ee * Ee;                  // [C][C]

    // 1) casts (x: fused straight+transpose, single fp32 read)
    k_cast_xt<<<dim3(Ee / 32, Cc / 32, Bb), 256, 0, stream>>>(x, xb, xbT);
    k_cast<<<cast_grid((long)Ee * Ee / 4), 256, 0, stream>>>(fc_w, fcwb, (long)Ee * Ee / 4);
    k_cast<<<cast_grid((long)Ee * Ee / 4), 256, 0, stream>>>(vfc_w, vfwb, (long)Ee * Ee / 4);
    k_cast<<<cast_grid((long)Cc * Cc / 4), 256, 0, stream>>>(altw, awb, (long)Cc * Cc / 4);

    const long sBCE = (long)Cc * Ee;
    const long sBCC = (long)Cc * Cc;
    dim3 blk(512);

    // 2) y[b][c][f] = sum_e xb[c,e] fcw[f,e] + fc_b[f]        M=C,N=E,K=E
    k_gemm256<1, 0><<<dim3(Cc/256, Ee/256, Bb), blk, 0, stream>>>(
        xb, fcwb, y, fc_b, Ee, Ee, sBCE, 0, sBCE, 1.f);

    // 3) vxT[b][f][k] = sum_e vfcw[f,e] xb[k,e] + vfc_b[f]    M=E,N=C,K=E (bias per row)
    k_gemm256<2, 0><<<dim3(Ee/256, Cc/256, Bb), blk, 0, stream>>>(
        vfwb, xb, vxT, vfc_b, Cc, Ee, 0, sBCE, sBCE, 1.f);

    // 4) z[b][k][e] = sum_c altw[k,c] xT[e,c] + alt_b[k]      M=C,N=E,K=C (bias per row)
    k_gemm256<2, 0><<<dim3(Cc/256, Ee/256, Bb), blk, 0, stream>>>(
        awb, xbT, z, altb, Ee, Cc, 0, sBCE, sBCE, 1.f);

    // 5) P[b][c][k] = (1/sqrt(C)) * sum_e y[c,e] z[k,e]       M=C,N=C,K=E
    k_gemm256<0, 0><<<dim3(Cc/256, Cc/256, Bb), blk, 0, stream>>>(
        y, z, P, nullptr, Cc, Ee, sBCE, sBCE, sBCC, 0.022097086912079608f);

    // 6) softmax rows of P (in place)
    k_softmax<<<Bb * Cc, 256, 0, stream>>>(P);

    // 7) out[b][c][e] = sum_k P[c,k] vxT[e,k] -> fp32         M=C,N=E,K=C
    k_gemm256<0, 1><<<dim3(Cc/256, Ee/256, Bb), blk, 0, stream>>>(
        P, vxT, out, nullptr, Ee, Cc, sBCC, sBCE, sBCE, 1.f);
}